// Round 1
// baseline (3719.218 us; speedup 1.0000x reference)
//
#include <hip/hip_runtime.h>
#include <math.h>

#define N_NODES   262144
#define N_EDGES   4194304
#define NUM_GRAPHS 1024

static __device__ __forceinline__ float sigmoidf_(float v) {
    return 1.0f / (1.0f + __expf(-v));
}

// ---------------------------------------------------------------------------
// Kernel 1: per-edge. hidden = silu(feat @ W1 + b1); atomically accumulate
// hidden into S[dst] (16 f32) and 1.0 into cnt[dst].
// ---------------------------------------------------------------------------
__global__ __launch_bounds__(256) void edge_kernel(
    const float* __restrict__ x, const float* __restrict__ pos,
    const int* __restrict__ ei,
    const float* __restrict__ w1, const float* __restrict__ b1,
    float* __restrict__ S, float* __restrict__ cnt)
{
    __shared__ __align__(16) float sw1[144];
    __shared__ float sb1[16];
    if (threadIdx.x < 144) sw1[threadIdx.x] = w1[threadIdx.x];
    if (threadIdx.x >= 192 && threadIdx.x < 208) sb1[threadIdx.x - 192] = b1[threadIdx.x - 192];
    __syncthreads();

    int e = blockIdx.x * 256 + threadIdx.x;
    if (e >= N_EDGES) return;
    int src = ei[e];
    int dst = ei[N_EDGES + e];

    float px = pos[3*src+0] - pos[3*dst+0];
    float py = pos[3*src+1] - pos[3*dst+1];
    float pz = pos[3*src+2] - pos[3*dst+2];
    float dist = sqrtf(px*px + py*py + pz*pz);

    float4 xd = *(const float4*)(x + 4*dst);
    float4 xs = *(const float4*)(x + 4*src);
    float feat[9] = {xd.x, xd.y, xd.z, xd.w, xs.x, xs.y, xs.z, xs.w, dist};

    float h[16];
    #pragma unroll
    for (int j = 0; j < 16; ++j) h[j] = sb1[j];
    #pragma unroll
    for (int i = 0; i < 9; ++i) {
        float f = feat[i];
        #pragma unroll
        for (int j4 = 0; j4 < 4; ++j4) {
            float4 w = *(const float4*)&sw1[i*16 + 4*j4];
            h[4*j4+0] = fmaf(f, w.x, h[4*j4+0]);
            h[4*j4+1] = fmaf(f, w.y, h[4*j4+1]);
            h[4*j4+2] = fmaf(f, w.z, h[4*j4+2]);
            h[4*j4+3] = fmaf(f, w.w, h[4*j4+3]);
        }
    }

    float* Sd = S + 16*dst;
    #pragma unroll
    for (int j = 0; j < 16; ++j) {
        float v = h[j];
        unsafeAtomicAdd(Sd + j, v * sigmoidf_(v));
    }
    unsafeAtomicAdd(cnt + dst, 1.0f);
}

// ---------------------------------------------------------------------------
// Kernel 2: per-node. h = relu((S@W2 + cnt*b2)/max(cnt,1)); s = softmax(h@Pw+Pb);
// write s; wave-segmented reduce of weighted = s (x) h into pooled[batch].
// ---------------------------------------------------------------------------
__global__ __launch_bounds__(256) void node_kernel(
    const float* __restrict__ S, const float* __restrict__ cnt,
    const int* __restrict__ batch,
    const float* __restrict__ w2, const float* __restrict__ b2,
    const float* __restrict__ pw, const float* __restrict__ pb,
    float* __restrict__ s_out, float* __restrict__ pooled)
{
    __shared__ __align__(16) float sw2[256];
    __shared__ float sb2[16];
    __shared__ float spw[32];
    __shared__ float spb[2];
    sw2[threadIdx.x] = w2[threadIdx.x];
    if (threadIdx.x < 16) sb2[threadIdx.x] = b2[threadIdx.x];
    else if (threadIdx.x >= 32 && threadIdx.x < 64) spw[threadIdx.x - 32] = pw[threadIdx.x - 32];
    else if (threadIdx.x >= 64 && threadIdx.x < 66) spb[threadIdx.x - 64] = pb[threadIdx.x - 64];
    __syncthreads();

    int n = blockIdx.x * 256 + threadIdx.x;
    float c = cnt[n];
    float inv = 1.0f / fmaxf(c, 1.0f);

    float Sv[16];
    const float4* Sp = (const float4*)(S + 16*n);
    #pragma unroll
    for (int i = 0; i < 4; ++i) {
        float4 v = Sp[i];
        Sv[4*i+0] = v.x; Sv[4*i+1] = v.y; Sv[4*i+2] = v.z; Sv[4*i+3] = v.w;
    }

    float h[16];
    #pragma unroll
    for (int j = 0; j < 16; ++j) h[j] = c * sb2[j];
    #pragma unroll
    for (int i = 0; i < 16; ++i) {
        float f = Sv[i];
        #pragma unroll
        for (int j4 = 0; j4 < 4; ++j4) {
            float4 w = *(const float4*)&sw2[i*16 + 4*j4];
            h[4*j4+0] = fmaf(f, w.x, h[4*j4+0]);
            h[4*j4+1] = fmaf(f, w.y, h[4*j4+1]);
            h[4*j4+2] = fmaf(f, w.z, h[4*j4+2]);
            h[4*j4+3] = fmaf(f, w.w, h[4*j4+3]);
        }
    }
    #pragma unroll
    for (int j = 0; j < 16; ++j) h[j] = fmaxf(h[j] * inv, 0.0f);

    float l0 = spb[0], l1 = spb[1];
    #pragma unroll
    for (int j = 0; j < 16; ++j) {
        l0 = fmaf(h[j], spw[2*j+0], l0);
        l1 = fmaf(h[j], spw[2*j+1], l1);
    }
    float m = fmaxf(l0, l1);
    float e0 = __expf(l0 - m), e1 = __expf(l1 - m);
    float r = 1.0f / (e0 + e1);
    float s0 = e0 * r, s1 = e1 * r;
    s_out[2*n+0] = s0;
    s_out[2*n+1] = s1;

    // weighted[k][i] = s_k * h_i  (pooled layout: g*32 + k*16 + i)
    float w[32];
    #pragma unroll
    for (int j = 0; j < 16; ++j) { w[j] = s0 * h[j]; w[16+j] = s1 * h[j]; }

    int b = batch[n];
    int lane = threadIdx.x & 63;
    // segmented suffix reduction within the wave (batch is sorted, nodes
    // consecutive across lanes): after the loop, each segment-head lane
    // holds the sum of its segment's values inside this wave.
    #pragma unroll
    for (int o = 1; o < 64; o <<= 1) {
        int bn = __shfl_down(b, o);
        bool take = (lane + o < 64) && (bn == b);
        #pragma unroll
        for (int cc = 0; cc < 32; ++cc) {
            float vn = __shfl_down(w[cc], o);
            if (take) w[cc] += vn;
        }
    }
    int bp = __shfl_up(b, 1);
    if (lane == 0 || bp != b) {
        float* pg = pooled + 32*b;
        #pragma unroll
        for (int cc = 0; cc < 32; ++cc) unsafeAtomicAdd(pg + cc, w[cc]);
    }
}

// ---------------------------------------------------------------------------
// Kernel 3: per-graph heads. z, recon, analytic potential + forces.
// ---------------------------------------------------------------------------
__global__ __launch_bounds__(256) void graph_kernel(
    const float* __restrict__ pooled,
    const float* __restrict__ toz_w, const float* __restrict__ toz_b,
    const float* __restrict__ vp_w1, const float* __restrict__ vp_b1,
    const float* __restrict__ vp_w2, const float* __restrict__ vp_b2,
    const float* __restrict__ bridge_w, const float* __restrict__ bridge_b,
    float* __restrict__ out_recon, float* __restrict__ out_z,
    float* __restrict__ out_forces, float* __restrict__ out_V)
{
    int g = blockIdx.x * 256 + threadIdx.x;
    if (g >= NUM_GRAPHS) return;

    const float* P = pooled + 32*g;
    float z[8];
    #pragma unroll
    for (int k = 0; k < 2; ++k) {
        #pragma unroll
        for (int d = 0; d < 4; ++d) {
            float acc = toz_b[d];
            #pragma unroll
            for (int i = 0; i < 16; ++i) acc = fmaf(P[16*k+i], toz_w[4*i+d], acc);
            z[4*k+d] = acc;
        }
    }
    #pragma unroll
    for (int i = 0; i < 8; ++i) out_z[8*g+i] = z[i];

    #pragma unroll
    for (int j = 0; j < 32; ++j) {
        float acc = bridge_b[j];
        #pragma unroll
        for (int i = 0; i < 8; ++i) acc = fmaf(z[i], bridge_w[32*i+j], acc);
        out_recon[32*g+j] = acc;
    }

    // q[k] = z[k][:2]; d = sqrt(|q0-q1|^2 + 1e-6)
    float d0 = z[0]-z[4], d1 = z[1]-z[5];
    float dd = sqrtf(d0*d0 + d1*d1 + 1e-6f);

    float V = vp_b2[0];
    float dV = 0.0f;
    #pragma unroll
    for (int j = 0; j < 32; ++j) {
        float w1 = vp_w1[j];
        float t  = fmaf(dd, w1, vp_b1[j]);
        float et = __expf(t);
        float sp = __logf(1.0f + et);      // softplus(t)
        float sg = et / (1.0f + et);       // sigmoid(t) = d softplus
        float w2 = vp_w2[j];
        V  = fmaf(sp, w2, V);
        dV = fmaf(sg * w1, w2, dV);
    }
    out_V[g] = V;

    float scale = dV / dd;      // dV/dq0 = scale*diff ; forces = -grad
    float gx = scale * d0, gy = scale * d1;
    out_forces[4*g+0] = -gx;
    out_forces[4*g+1] = -gy;
    out_forces[4*g+2] =  gx;
    out_forces[4*g+3] =  gy;
}

// ---------------------------------------------------------------------------
extern "C" void kernel_launch(void* const* d_in, const int* in_sizes, int n_in,
                              void* d_out, int out_size, void* d_ws, size_t ws_size,
                              hipStream_t stream) {
    const float* x        = (const float*)d_in[0];
    const float* pos      = (const float*)d_in[1];
    const int*   ei       = (const int*)  d_in[2];
    const int*   batch    = (const int*)  d_in[3];
    const float* enc_w1   = (const float*)d_in[4];
    const float* enc_b1   = (const float*)d_in[5];
    const float* enc_w2   = (const float*)d_in[6];
    const float* enc_b2   = (const float*)d_in[7];
    const float* pool_w   = (const float*)d_in[8];
    const float* pool_b   = (const float*)d_in[9];
    const float* toz_w    = (const float*)d_in[10];
    const float* toz_b    = (const float*)d_in[11];
    const float* vp_w1    = (const float*)d_in[12];
    const float* vp_b1    = (const float*)d_in[13];
    const float* vp_w2    = (const float*)d_in[14];
    const float* vp_b2    = (const float*)d_in[15];
    const float* bridge_w = (const float*)d_in[16];
    const float* bridge_b = (const float*)d_in[17];

    float* S      = (float*)d_ws;                 // N_NODES*16
    float* cnt    = S + (size_t)N_NODES*16;       // N_NODES
    float* pooled = cnt + N_NODES;                // NUM_GRAPHS*32

    float* out        = (float*)d_out;
    float* out_recon  = out;                        // 1024*8*4 = 32768
    float* out_z      = out_recon + 1024*32;        // 1024*2*4 = 8192
    float* out_s      = out_z + 1024*8;             // 262144*2 = 524288
    float* out_forces = out_s + (size_t)N_NODES*2;  // 1024*2*2 = 4096
    float* out_V      = out_forces + 1024*4;        // 1024

    hipMemsetAsync(d_ws, 0,
                   ((size_t)N_NODES*17 + (size_t)NUM_GRAPHS*32) * sizeof(float),
                   stream);

    edge_kernel<<<N_EDGES/256, 256, 0, stream>>>(x, pos, ei, enc_w1, enc_b1, S, cnt);
    node_kernel<<<N_NODES/256, 256, 0, stream>>>(S, cnt, batch, enc_w2, enc_b2,
                                                 pool_w, pool_b, out_s, pooled);
    graph_kernel<<<NUM_GRAPHS/256, 256, 0, stream>>>(pooled, toz_w, toz_b,
                                                     vp_w1, vp_b1, vp_w2, vp_b2,
                                                     bridge_w, bridge_b,
                                                     out_recon, out_z, out_forces, out_V);
}

// Round 2
// 794.025 us; speedup vs baseline: 4.6840x; 4.6840x over previous
//
#include <hip/hip_runtime.h>
#include <math.h>

#define N_NODES   262144
#define N_EDGES   4194304
#define NUM_GRAPHS 1024

static __device__ __forceinline__ float sigmoidf_(float v) {
    return 1.0f / (1.0f + __expf(-v));
}

// ---------------------------------------------------------------------------
// Pass A: histogram of dst degrees.
// ---------------------------------------------------------------------------
__global__ __launch_bounds__(256) void hist_kernel(
    const int* __restrict__ ei, int* __restrict__ deg)
{
    int e = blockIdx.x * 256 + threadIdx.x;
    int dst = ei[N_EDGES + e];
    atomicAdd(deg + dst, 1);
}

// ---------------------------------------------------------------------------
// Pass B1: per-block exclusive scan of deg -> rowptr (block-local), blocksum.
// ---------------------------------------------------------------------------
__global__ __launch_bounds__(256) void scan1_kernel(
    const int* __restrict__ deg, int* __restrict__ rowptr,
    int* __restrict__ blocksum)
{
    int i = blockIdx.x * 256 + threadIdx.x;
    int v = deg[i];
    int lane = threadIdx.x & 63, wid = threadIdx.x >> 6;
    int s = v;
    #pragma unroll
    for (int o = 1; o < 64; o <<= 1) {
        int t = __shfl_up(s, o);
        if (lane >= o) s += t;
    }
    __shared__ int wsum[4];
    if (lane == 63) wsum[wid] = s;
    __syncthreads();
    int base = 0;
    #pragma unroll
    for (int w = 0; w < 4; ++w) if (w < wid) base += wsum[w];
    rowptr[i] = base + s - v;          // exclusive within block
    if (threadIdx.x == 255) blocksum[blockIdx.x] = base + s;
}

// ---------------------------------------------------------------------------
// Pass B2: exclusive scan of the 1024 block sums, in place. One block.
// ---------------------------------------------------------------------------
__global__ __launch_bounds__(1024) void scan2_kernel(int* __restrict__ blocksum)
{
    int i = threadIdx.x;
    int v = blocksum[i];
    int lane = i & 63, wid = i >> 6;
    int s = v;
    #pragma unroll
    for (int o = 1; o < 64; o <<= 1) {
        int t = __shfl_up(s, o);
        if (lane >= o) s += t;
    }
    __shared__ int ws[16];
    if (lane == 63) ws[wid] = s;
    __syncthreads();
    if (wid == 0 && lane < 16) {
        int w = ws[lane];
        int sw = w;
        #pragma unroll
        for (int o = 1; o < 16; o <<= 1) {
            int t = __shfl_up(sw, o);
            if (lane >= o) sw += t;
        }
        ws[lane] = sw - w;             // exclusive wave offsets
    }
    __syncthreads();
    blocksum[i] = ws[wid] + s - v;     // exclusive global scan
}

// ---------------------------------------------------------------------------
// Pass B3: add block offsets; produce final rowptr and a scatter cursor copy.
// ---------------------------------------------------------------------------
__global__ __launch_bounds__(256) void scan3_kernel(
    int* __restrict__ rowptr, const int* __restrict__ blocksum,
    int* __restrict__ cursor)
{
    int i = blockIdx.x * 256 + threadIdx.x;
    int r = rowptr[i] + blocksum[blockIdx.x];
    rowptr[i] = r;
    cursor[i] = r;
}

// ---------------------------------------------------------------------------
// Pass C: scatter src ids into CSR slots.
// ---------------------------------------------------------------------------
__global__ __launch_bounds__(256) void scatter_kernel(
    const int* __restrict__ ei, int* __restrict__ cursor,
    int* __restrict__ csr_src)
{
    int e = blockIdx.x * 256 + threadIdx.x;
    int src = ei[e];
    int dst = ei[N_EDGES + e];
    int p = atomicAdd(cursor + dst, 1);
    csr_src[p] = src;
}

// ---------------------------------------------------------------------------
// Pass D (fused): per-node gather + edge MLP + mean/relu + node MLP + softmax
// + attention pooling (wave-segmented reduction over sorted batch).
// ---------------------------------------------------------------------------
__global__ __launch_bounds__(256) void fused_node_kernel(
    const float* __restrict__ x, const float* __restrict__ pos,
    const int* __restrict__ rowptr, const int* __restrict__ deg,
    const int* __restrict__ csr_src, const int* __restrict__ batch,
    const float* __restrict__ w1, const float* __restrict__ b1,
    const float* __restrict__ w2, const float* __restrict__ b2,
    const float* __restrict__ pw, const float* __restrict__ pb,
    float* __restrict__ s_out, float* __restrict__ pooled)
{
    __shared__ __align__(16) float sw1[144];
    __shared__ float sb1[16];
    __shared__ __align__(16) float sw2[256];
    __shared__ float sb2[16];
    __shared__ float spw[32];
    __shared__ float spb[2];
    if (threadIdx.x < 144) sw1[threadIdx.x] = w1[threadIdx.x];
    if (threadIdx.x >= 144 && threadIdx.x < 160) sb1[threadIdx.x - 144] = b1[threadIdx.x - 144];
    if (threadIdx.x >= 160 && threadIdx.x < 176) sb2[threadIdx.x - 160] = b2[threadIdx.x - 160];
    if (threadIdx.x >= 176 && threadIdx.x < 208) spw[threadIdx.x - 176] = pw[threadIdx.x - 176];
    if (threadIdx.x >= 208 && threadIdx.x < 210) spb[threadIdx.x - 208] = pb[threadIdx.x - 208];
    {
        int t = threadIdx.x;  // 256 threads load 256 w2 entries
        sw2[t] = w2[t];
    }
    __syncthreads();

    int n = blockIdx.x * 256 + threadIdx.x;
    int r0 = rowptr[n];
    int dg = deg[n];

    float pdx = pos[3*n+0], pdy = pos[3*n+1], pdz = pos[3*n+2];
    float4 xd = *(const float4*)(x + 4*n);

    float acc[16];
    #pragma unroll
    for (int j = 0; j < 16; ++j) acc[j] = 0.0f;

    for (int k = 0; k < dg; ++k) {
        int src = csr_src[r0 + k];
        float px = pos[3*src+0] - pdx;
        float py = pos[3*src+1] - pdy;
        float pz = pos[3*src+2] - pdz;
        float dist = sqrtf(px*px + py*py + pz*pz);
        float4 xs = *(const float4*)(x + 4*src);
        float feat[9] = {xd.x, xd.y, xd.z, xd.w, xs.x, xs.y, xs.z, xs.w, dist};

        float h[16];
        #pragma unroll
        for (int j = 0; j < 16; ++j) h[j] = sb1[j];
        #pragma unroll
        for (int i = 0; i < 9; ++i) {
            float f = feat[i];
            #pragma unroll
            for (int j4 = 0; j4 < 4; ++j4) {
                float4 w = *(const float4*)&sw1[i*16 + 4*j4];
                h[4*j4+0] = fmaf(f, w.x, h[4*j4+0]);
                h[4*j4+1] = fmaf(f, w.y, h[4*j4+1]);
                h[4*j4+2] = fmaf(f, w.z, h[4*j4+2]);
                h[4*j4+3] = fmaf(f, w.w, h[4*j4+3]);
            }
        }
        #pragma unroll
        for (int j = 0; j < 16; ++j) acc[j] += h[j] * sigmoidf_(h[j]);
    }

    // node MLP: h = relu((acc @ W2 + cnt*b2) / max(cnt,1))
    float c = (float)dg;
    float inv = 1.0f / fmaxf(c, 1.0f);
    float h[16];
    #pragma unroll
    for (int j = 0; j < 16; ++j) h[j] = c * sb2[j];
    #pragma unroll
    for (int i = 0; i < 16; ++i) {
        float f = acc[i];
        #pragma unroll
        for (int j4 = 0; j4 < 4; ++j4) {
            float4 w = *(const float4*)&sw2[i*16 + 4*j4];
            h[4*j4+0] = fmaf(f, w.x, h[4*j4+0]);
            h[4*j4+1] = fmaf(f, w.y, h[4*j4+1]);
            h[4*j4+2] = fmaf(f, w.z, h[4*j4+2]);
            h[4*j4+3] = fmaf(f, w.w, h[4*j4+3]);
        }
    }
    #pragma unroll
    for (int j = 0; j < 16; ++j) h[j] = fmaxf(h[j] * inv, 0.0f);

    float l0 = spb[0], l1 = spb[1];
    #pragma unroll
    for (int j = 0; j < 16; ++j) {
        l0 = fmaf(h[j], spw[2*j+0], l0);
        l1 = fmaf(h[j], spw[2*j+1], l1);
    }
    float m = fmaxf(l0, l1);
    float e0 = __expf(l0 - m), e1 = __expf(l1 - m);
    float r = 1.0f / (e0 + e1);
    float s0 = e0 * r, s1 = e1 * r;
    s_out[2*n+0] = s0;
    s_out[2*n+1] = s1;

    // weighted[k][i] = s_k * h_i  (pooled layout: g*32 + k*16 + i)
    float w[32];
    #pragma unroll
    for (int j = 0; j < 16; ++j) { w[j] = s0 * h[j]; w[16+j] = s1 * h[j]; }

    int b = batch[n];
    int lane = threadIdx.x & 63;
    #pragma unroll
    for (int o = 1; o < 64; o <<= 1) {
        int bn = __shfl_down(b, o);
        bool take = (lane + o < 64) && (bn == b);
        #pragma unroll
        for (int cc = 0; cc < 32; ++cc) {
            float vn = __shfl_down(w[cc], o);
            if (take) w[cc] += vn;
        }
    }
    int bp = __shfl_up(b, 1);
    if (lane == 0 || bp != b) {
        float* pg = pooled + 32*b;
        #pragma unroll
        for (int cc = 0; cc < 32; ++cc) unsafeAtomicAdd(pg + cc, w[cc]);
    }
}

// ---------------------------------------------------------------------------
// Per-graph heads. z, recon, analytic potential + forces.
// ---------------------------------------------------------------------------
__global__ __launch_bounds__(256) void graph_kernel(
    const float* __restrict__ pooled,
    const float* __restrict__ toz_w, const float* __restrict__ toz_b,
    const float* __restrict__ vp_w1, const float* __restrict__ vp_b1,
    const float* __restrict__ vp_w2, const float* __restrict__ vp_b2,
    const float* __restrict__ bridge_w, const float* __restrict__ bridge_b,
    float* __restrict__ out_recon, float* __restrict__ out_z,
    float* __restrict__ out_forces, float* __restrict__ out_V)
{
    int g = blockIdx.x * 256 + threadIdx.x;
    if (g >= NUM_GRAPHS) return;

    const float* P = pooled + 32*g;
    float z[8];
    #pragma unroll
    for (int k = 0; k < 2; ++k) {
        #pragma unroll
        for (int d = 0; d < 4; ++d) {
            float a = toz_b[d];
            #pragma unroll
            for (int i = 0; i < 16; ++i) a = fmaf(P[16*k+i], toz_w[4*i+d], a);
            z[4*k+d] = a;
        }
    }
    #pragma unroll
    for (int i = 0; i < 8; ++i) out_z[8*g+i] = z[i];

    #pragma unroll
    for (int j = 0; j < 32; ++j) {
        float a = bridge_b[j];
        #pragma unroll
        for (int i = 0; i < 8; ++i) a = fmaf(z[i], bridge_w[32*i+j], a);
        out_recon[32*g+j] = a;
    }

    float d0 = z[0]-z[4], d1 = z[1]-z[5];
    float dd = sqrtf(d0*d0 + d1*d1 + 1e-6f);

    float V = vp_b2[0];
    float dV = 0.0f;
    #pragma unroll
    for (int j = 0; j < 32; ++j) {
        float w1 = vp_w1[j];
        float t  = fmaf(dd, w1, vp_b1[j]);
        float et = __expf(t);
        float sp = __logf(1.0f + et);
        float sg = et / (1.0f + et);
        float w2 = vp_w2[j];
        V  = fmaf(sp, w2, V);
        dV = fmaf(sg * w1, w2, dV);
    }
    out_V[g] = V;

    float scale = dV / dd;
    float gx = scale * d0, gy = scale * d1;
    out_forces[4*g+0] = -gx;
    out_forces[4*g+1] = -gy;
    out_forces[4*g+2] =  gx;
    out_forces[4*g+3] =  gy;
}

// ---------------------------------------------------------------------------
extern "C" void kernel_launch(void* const* d_in, const int* in_sizes, int n_in,
                              void* d_out, int out_size, void* d_ws, size_t ws_size,
                              hipStream_t stream) {
    const float* x        = (const float*)d_in[0];
    const float* pos      = (const float*)d_in[1];
    const int*   ei       = (const int*)  d_in[2];
    const int*   batch    = (const int*)  d_in[3];
    const float* enc_w1   = (const float*)d_in[4];
    const float* enc_b1   = (const float*)d_in[5];
    const float* enc_w2   = (const float*)d_in[6];
    const float* enc_b2   = (const float*)d_in[7];
    const float* pool_w   = (const float*)d_in[8];
    const float* pool_b   = (const float*)d_in[9];
    const float* toz_w    = (const float*)d_in[10];
    const float* toz_b    = (const float*)d_in[11];
    const float* vp_w1    = (const float*)d_in[12];
    const float* vp_b1    = (const float*)d_in[13];
    const float* vp_w2    = (const float*)d_in[14];
    const float* vp_b2    = (const float*)d_in[15];
    const float* bridge_w = (const float*)d_in[16];
    const float* bridge_b = (const float*)d_in[17];

    // workspace layout (4B elements)
    int*   deg      = (int*)d_ws;                       // 262144
    float* pooled   = (float*)d_ws + N_NODES;           // 32768  (zeroed w/ deg)
    int*   rowptr   = (int*)d_ws + N_NODES + 32768;     // 262144
    int*   cursor   = rowptr + N_NODES;                 // 262144
    int*   blocksum = cursor + N_NODES;                 // 1024
    int*   csr_src  = blocksum + 1024;                  // 4194304
    // total ~20.1 MB

    float* out        = (float*)d_out;
    float* out_recon  = out;                        // 1024*32
    float* out_z      = out_recon + 1024*32;        // 1024*8
    float* out_s      = out_z + 1024*8;             // 262144*2
    float* out_forces = out_s + (size_t)N_NODES*2;  // 1024*4
    float* out_V      = out_forces + 1024*4;        // 1024

    hipMemsetAsync(d_ws, 0, (size_t)(N_NODES + 32768) * sizeof(float), stream);

    hist_kernel   <<<N_EDGES/256, 256, 0, stream>>>(ei, deg);
    scan1_kernel  <<<N_NODES/256, 256, 0, stream>>>(deg, rowptr, blocksum);
    scan2_kernel  <<<1, 1024, 0, stream>>>(blocksum);
    scan3_kernel  <<<N_NODES/256, 256, 0, stream>>>(rowptr, blocksum, cursor);
    scatter_kernel<<<N_EDGES/256, 256, 0, stream>>>(ei, cursor, csr_src);
    fused_node_kernel<<<N_NODES/256, 256, 0, stream>>>(
        x, pos, rowptr, deg, csr_src, batch,
        enc_w1, enc_b1, enc_w2, enc_b2, pool_w, pool_b, out_s, pooled);
    graph_kernel<<<NUM_GRAPHS/256, 256, 0, stream>>>(
        pooled, toz_w, toz_b, vp_w1, vp_b1, vp_w2, vp_b2,
        bridge_w, bridge_b, out_recon, out_z, out_forces, out_V);
}

// Round 3
// 379.574 us; speedup vs baseline: 9.7984x; 2.0919x over previous
//
#include <hip/hip_runtime.h>
#include <math.h>

#define N_NODES   262144
#define N_EDGES   4194304
#define NUM_GRAPHS 1024
#define NB        512          // coarse buckets (dst >> 9)
#define BN        512          // nodes per bucket
#define CAP       12288        // LDS staging cap per bucket (mean 8192, 45 sigma)

static __device__ __forceinline__ float sigmoidf_(float v) {
    return 1.0f / (1.0f + __expf(-v));
}

// ---------------------------------------------------------------------------
// K1: coarse bucket histogram. 256 blocks x 256 thr x 64 edges.
// ---------------------------------------------------------------------------
__global__ __launch_bounds__(256) void bucket_hist_kernel(
    const int* __restrict__ ei, int* __restrict__ bucket_total)
{
    __shared__ int cnt[NB];
    cnt[threadIdx.x] = 0; cnt[threadIdx.x + 256] = 0;
    __syncthreads();
    int base = blockIdx.x * 16384;
    #pragma unroll 4
    for (int i = 0; i < 64; ++i) {
        int dst = ei[N_EDGES + base + i*256 + threadIdx.x];
        atomicAdd(&cnt[dst >> 9], 1);
    }
    __syncthreads();
    int c0 = cnt[threadIdx.x], c1 = cnt[threadIdx.x + 256];
    if (c0) atomicAdd(bucket_total + threadIdx.x, c0);
    if (c1) atomicAdd(bucket_total + threadIdx.x + 256, c1);
}

// ---------------------------------------------------------------------------
// K2: exclusive scan of 512 bucket totals -> bucket_base, bucket_cursor.
// ---------------------------------------------------------------------------
__global__ __launch_bounds__(512) void bucket_scan_kernel(
    const int* __restrict__ bucket_total,
    int* __restrict__ bucket_base, int* __restrict__ bucket_cursor)
{
    int i = threadIdx.x;
    int v = bucket_total[i];
    int lane = i & 63, wid = i >> 6;
    int s = v;
    #pragma unroll
    for (int o = 1; o < 64; o <<= 1) {
        int t = __shfl_up(s, o);
        if (lane >= o) s += t;
    }
    __shared__ int ws[8];
    if (lane == 63) ws[wid] = s;
    __syncthreads();
    int b = 0;
    #pragma unroll
    for (int w = 0; w < 8; ++w) if (w < wid) b += ws[w];
    int excl = b + s - v;
    bucket_base[i]   = excl;
    bucket_cursor[i] = excl;
}

// ---------------------------------------------------------------------------
// K3: binning. 1024 blocks x 256 thr x 16 edges. Pack (dst&511)<<18 | src.
// ---------------------------------------------------------------------------
__global__ __launch_bounds__(256) void binning_kernel(
    const int* __restrict__ ei, int* __restrict__ bucket_cursor,
    int* __restrict__ staged)
{
    __shared__ int cnt[NB];
    __shared__ int runbase[NB];
    cnt[threadIdx.x] = 0; cnt[threadIdx.x + 256] = 0;
    __syncthreads();

    int base = blockIdx.x * 4096;
    int ds[16];
    #pragma unroll
    for (int i = 0; i < 16; ++i) {
        ds[i] = ei[N_EDGES + base + i*256 + threadIdx.x];
        atomicAdd(&cnt[ds[i] >> 9], 1);
    }
    __syncthreads();
    {
        int k0 = threadIdx.x, k1 = threadIdx.x + 256;
        int c0 = cnt[k0], c1 = cnt[k1];
        runbase[k0] = c0 ? atomicAdd(bucket_cursor + k0, c0) : 0;
        runbase[k1] = c1 ? atomicAdd(bucket_cursor + k1, c1) : 0;
        cnt[k0] = 0; cnt[k1] = 0;
    }
    __syncthreads();
    #pragma unroll
    for (int i = 0; i < 16; ++i) {
        int e   = base + i*256 + threadIdx.x;
        int src = ei[e];
        int dst = ds[i];
        int bk  = dst >> 9;
        int r   = atomicAdd(&cnt[bk], 1);
        staged[runbase[bk] + r] = ((dst & 511) << 18) | src;
    }
}

// ---------------------------------------------------------------------------
// K4: per-bucket CSR build. 512 blocks, one bucket each. In-place permute of
// staged -> csr (same array) via LDS staging. Writes rowptr/deg.
// ---------------------------------------------------------------------------
__global__ __launch_bounds__(256) void bucket_csr_kernel(
    int* __restrict__ staged, const int* __restrict__ bucket_base,
    const int* __restrict__ bucket_total,
    int* __restrict__ rowptr, int* __restrict__ deg)
{
    __shared__ int offs[BN];
    __shared__ int stage[CAP];
    __shared__ int wsum[4];

    int bkt  = blockIdx.x;
    int gbase = bucket_base[bkt];
    int cnt  = bucket_total[bkt];
    if (cnt > CAP) cnt = CAP;   // never in practice

    offs[threadIdx.x] = 0; offs[threadIdx.x + 256] = 0;
    __syncthreads();

    for (int i = threadIdx.x; i < cnt; i += 256) {
        int p = staged[gbase + i];
        stage[i] = p;
        atomicAdd(&offs[p >> 18], 1);
    }
    __syncthreads();

    // block scan of 512 counters (2 per thread)
    int v0 = offs[2*threadIdx.x], v1 = offs[2*threadIdx.x + 1];
    int s = v0 + v1;
    int lane = threadIdx.x & 63, wid = threadIdx.x >> 6;
    int inc = s;
    #pragma unroll
    for (int o = 1; o < 64; o <<= 1) {
        int t = __shfl_up(inc, o);
        if (lane >= o) inc += t;
    }
    if (lane == 63) wsum[wid] = inc;
    __syncthreads();
    int wb = 0;
    #pragma unroll
    for (int w = 0; w < 4; ++w) if (w < wid) wb += wsum[w];
    int excl = wb + inc - s;

    int n = bkt * BN + 2*threadIdx.x;
    rowptr[n]   = gbase + excl;
    rowptr[n+1] = gbase + excl + v0;
    deg[n]   = v0;
    deg[n+1] = v1;
    offs[2*threadIdx.x]     = excl;        // cursors (only this thread touches)
    offs[2*threadIdx.x + 1] = excl + v0;
    __syncthreads();

    for (int i = threadIdx.x; i < cnt; i += 256) {
        int p  = stage[i];
        int lo = p >> 18;
        int r  = atomicAdd(&offs[lo], 1);
        staged[gbase + r] = p & 0x3FFFF;   // src
    }
}

// ---------------------------------------------------------------------------
// K5 (fused): per-node gather + edge MLP + mean/relu + node MLP + softmax
// + attention pooling (wave-segmented reduction over sorted batch).
// ---------------------------------------------------------------------------
__global__ __launch_bounds__(256) void fused_node_kernel(
    const float* __restrict__ x, const float* __restrict__ pos,
    const int* __restrict__ rowptr, const int* __restrict__ deg,
    const int* __restrict__ csr_src, const int* __restrict__ batch,
    const float* __restrict__ w1, const float* __restrict__ b1,
    const float* __restrict__ w2, const float* __restrict__ b2,
    const float* __restrict__ pw, const float* __restrict__ pb,
    float* __restrict__ s_out, float* __restrict__ pooled)
{
    __shared__ __align__(16) float sw1[144];
    __shared__ float sb1[16];
    __shared__ __align__(16) float sw2[256];
    __shared__ float sb2[16];
    __shared__ float spw[32];
    __shared__ float spb[2];
    if (threadIdx.x < 144) sw1[threadIdx.x] = w1[threadIdx.x];
    if (threadIdx.x >= 144 && threadIdx.x < 160) sb1[threadIdx.x - 144] = b1[threadIdx.x - 144];
    if (threadIdx.x >= 160 && threadIdx.x < 176) sb2[threadIdx.x - 160] = b2[threadIdx.x - 160];
    if (threadIdx.x >= 176 && threadIdx.x < 208) spw[threadIdx.x - 176] = pw[threadIdx.x - 176];
    if (threadIdx.x >= 208 && threadIdx.x < 210) spb[threadIdx.x - 208] = pb[threadIdx.x - 208];
    sw2[threadIdx.x] = w2[threadIdx.x];
    __syncthreads();

    int n = blockIdx.x * 256 + threadIdx.x;
    int r0 = rowptr[n];
    int dg = deg[n];

    float pdx = pos[3*n+0], pdy = pos[3*n+1], pdz = pos[3*n+2];
    float4 xd = *(const float4*)(x + 4*n);

    float acc[16];
    #pragma unroll
    for (int j = 0; j < 16; ++j) acc[j] = 0.0f;

    for (int k = 0; k < dg; ++k) {
        int src = csr_src[r0 + k];
        float px = pos[3*src+0] - pdx;
        float py = pos[3*src+1] - pdy;
        float pz = pos[3*src+2] - pdz;
        float dist = sqrtf(px*px + py*py + pz*pz);
        float4 xs = *(const float4*)(x + 4*src);
        float feat[9] = {xd.x, xd.y, xd.z, xd.w, xs.x, xs.y, xs.z, xs.w, dist};

        float h[16];
        #pragma unroll
        for (int j = 0; j < 16; ++j) h[j] = sb1[j];
        #pragma unroll
        for (int i = 0; i < 9; ++i) {
            float f = feat[i];
            #pragma unroll
            for (int j4 = 0; j4 < 4; ++j4) {
                float4 w = *(const float4*)&sw1[i*16 + 4*j4];
                h[4*j4+0] = fmaf(f, w.x, h[4*j4+0]);
                h[4*j4+1] = fmaf(f, w.y, h[4*j4+1]);
                h[4*j4+2] = fmaf(f, w.z, h[4*j4+2]);
                h[4*j4+3] = fmaf(f, w.w, h[4*j4+3]);
            }
        }
        #pragma unroll
        for (int j = 0; j < 16; ++j) acc[j] += h[j] * sigmoidf_(h[j]);
    }

    float c = (float)dg;
    float inv = 1.0f / fmaxf(c, 1.0f);
    float h[16];
    #pragma unroll
    for (int j = 0; j < 16; ++j) h[j] = c * sb2[j];
    #pragma unroll
    for (int i = 0; i < 16; ++i) {
        float f = acc[i];
        #pragma unroll
        for (int j4 = 0; j4 < 4; ++j4) {
            float4 w = *(const float4*)&sw2[i*16 + 4*j4];
            h[4*j4+0] = fmaf(f, w.x, h[4*j4+0]);
            h[4*j4+1] = fmaf(f, w.y, h[4*j4+1]);
            h[4*j4+2] = fmaf(f, w.z, h[4*j4+2]);
            h[4*j4+3] = fmaf(f, w.w, h[4*j4+3]);
        }
    }
    #pragma unroll
    for (int j = 0; j < 16; ++j) h[j] = fmaxf(h[j] * inv, 0.0f);

    float l0 = spb[0], l1 = spb[1];
    #pragma unroll
    for (int j = 0; j < 16; ++j) {
        l0 = fmaf(h[j], spw[2*j+0], l0);
        l1 = fmaf(h[j], spw[2*j+1], l1);
    }
    float m = fmaxf(l0, l1);
    float e0 = __expf(l0 - m), e1 = __expf(l1 - m);
    float r = 1.0f / (e0 + e1);
    float s0 = e0 * r, s1 = e1 * r;
    s_out[2*n+0] = s0;
    s_out[2*n+1] = s1;

    float w[32];
    #pragma unroll
    for (int j = 0; j < 16; ++j) { w[j] = s0 * h[j]; w[16+j] = s1 * h[j]; }

    int b = batch[n];
    int lane = threadIdx.x & 63;
    #pragma unroll
    for (int o = 1; o < 64; o <<= 1) {
        int bn = __shfl_down(b, o);
        bool take = (lane + o < 64) && (bn == b);
        #pragma unroll
        for (int cc = 0; cc < 32; ++cc) {
            float vn = __shfl_down(w[cc], o);
            if (take) w[cc] += vn;
        }
    }
    int bp = __shfl_up(b, 1);
    if (lane == 0 || bp != b) {
        float* pg = pooled + 32*b;
        #pragma unroll
        for (int cc = 0; cc < 32; ++cc) unsafeAtomicAdd(pg + cc, w[cc]);
    }
}

// ---------------------------------------------------------------------------
// K6: per-graph heads. z, recon, analytic potential + forces.
// ---------------------------------------------------------------------------
__global__ __launch_bounds__(256) void graph_kernel(
    const float* __restrict__ pooled,
    const float* __restrict__ toz_w, const float* __restrict__ toz_b,
    const float* __restrict__ vp_w1, const float* __restrict__ vp_b1,
    const float* __restrict__ vp_w2, const float* __restrict__ vp_b2,
    const float* __restrict__ bridge_w, const float* __restrict__ bridge_b,
    float* __restrict__ out_recon, float* __restrict__ out_z,
    float* __restrict__ out_forces, float* __restrict__ out_V)
{
    int g = blockIdx.x * 256 + threadIdx.x;
    if (g >= NUM_GRAPHS) return;

    const float* P = pooled + 32*g;
    float z[8];
    #pragma unroll
    for (int k = 0; k < 2; ++k) {
        #pragma unroll
        for (int d = 0; d < 4; ++d) {
            float a = toz_b[d];
            #pragma unroll
            for (int i = 0; i < 16; ++i) a = fmaf(P[16*k+i], toz_w[4*i+d], a);
            z[4*k+d] = a;
        }
    }
    #pragma unroll
    for (int i = 0; i < 8; ++i) out_z[8*g+i] = z[i];

    #pragma unroll
    for (int j = 0; j < 32; ++j) {
        float a = bridge_b[j];
        #pragma unroll
        for (int i = 0; i < 8; ++i) a = fmaf(z[i], bridge_w[32*i+j], a);
        out_recon[32*g+j] = a;
    }

    float d0 = z[0]-z[4], d1 = z[1]-z[5];
    float dd = sqrtf(d0*d0 + d1*d1 + 1e-6f);

    float V = vp_b2[0];
    float dV = 0.0f;
    #pragma unroll
    for (int j = 0; j < 32; ++j) {
        float w1 = vp_w1[j];
        float t  = fmaf(dd, w1, vp_b1[j]);
        float et = __expf(t);
        float sp = __logf(1.0f + et);
        float sg = et / (1.0f + et);
        float w2 = vp_w2[j];
        V  = fmaf(sp, w2, V);
        dV = fmaf(sg * w1, w2, dV);
    }
    out_V[g] = V;

    float scale = dV / dd;
    float gx = scale * d0, gy = scale * d1;
    out_forces[4*g+0] = -gx;
    out_forces[4*g+1] = -gy;
    out_forces[4*g+2] =  gx;
    out_forces[4*g+3] =  gy;
}

// ---------------------------------------------------------------------------
extern "C" void kernel_launch(void* const* d_in, const int* in_sizes, int n_in,
                              void* d_out, int out_size, void* d_ws, size_t ws_size,
                              hipStream_t stream) {
    const float* x        = (const float*)d_in[0];
    const float* pos      = (const float*)d_in[1];
    const int*   ei       = (const int*)  d_in[2];
    const int*   batch    = (const int*)  d_in[3];
    const float* enc_w1   = (const float*)d_in[4];
    const float* enc_b1   = (const float*)d_in[5];
    const float* enc_w2   = (const float*)d_in[6];
    const float* enc_b2   = (const float*)d_in[7];
    const float* pool_w   = (const float*)d_in[8];
    const float* pool_b   = (const float*)d_in[9];
    const float* toz_w    = (const float*)d_in[10];
    const float* toz_b    = (const float*)d_in[11];
    const float* vp_w1    = (const float*)d_in[12];
    const float* vp_b1    = (const float*)d_in[13];
    const float* vp_w2    = (const float*)d_in[14];
    const float* vp_b2    = (const float*)d_in[15];
    const float* bridge_w = (const float*)d_in[16];
    const float* bridge_b = (const float*)d_in[17];

    // workspace layout (4B units) ~19 MB
    int*   bucket_total  = (int*)d_ws;                       // 512
    float* pooled        = (float*)d_ws + NB;                // 32768 (zeroed w/ totals)
    int*   bucket_base   = (int*)d_ws + NB + 32768;          // 512
    int*   bucket_cursor = bucket_base + NB;                 // 512
    int*   rowptr        = bucket_cursor + NB;               // 262144
    int*   deg           = rowptr + N_NODES;                 // 262144
    int*   staged        = deg + N_NODES;                    // 4194304 (becomes csr)

    float* out        = (float*)d_out;
    float* out_recon  = out;                        // 1024*32
    float* out_z      = out_recon + 1024*32;        // 1024*8
    float* out_s      = out_z + 1024*8;             // 262144*2
    float* out_forces = out_s + (size_t)N_NODES*2;  // 1024*4
    float* out_V      = out_forces + 1024*4;        // 1024

    hipMemsetAsync(d_ws, 0, (size_t)(NB + 32768) * sizeof(float), stream);

    bucket_hist_kernel<<<256, 256, 0, stream>>>(ei, bucket_total);
    bucket_scan_kernel<<<1, 512, 0, stream>>>(bucket_total, bucket_base, bucket_cursor);
    binning_kernel    <<<1024, 256, 0, stream>>>(ei, bucket_cursor, staged);
    bucket_csr_kernel <<<NB, 256, 0, stream>>>(staged, bucket_base, bucket_total,
                                               rowptr, deg);
    fused_node_kernel <<<N_NODES/256, 256, 0, stream>>>(
        x, pos, rowptr, deg, staged, batch,
        enc_w1, enc_b1, enc_w2, enc_b2, pool_w, pool_b, out_s, pooled);
    graph_kernel<<<NUM_GRAPHS/256, 256, 0, stream>>>(
        pooled, toz_w, toz_b, vp_w1, vp_b1, vp_w2, vp_b2,
        bridge_w, bridge_b, out_recon, out_z, out_forces, out_V);
}